// Round 1
// baseline (218.251 us; speedup 1.0000x reference)
//
#include <hip/hip_runtime.h>

#define T_SEQ 2048
#define DHEAD 128
#define NBH 16
#define SCALE 0.08838834764831845f

typedef unsigned short u16;
typedef u16 u16x4 __attribute__((ext_vector_type(4)));
typedef u16 u16x8 __attribute__((ext_vector_type(8)));
typedef __bf16 bf16x8 __attribute__((ext_vector_type(8)));
typedef float f32x4 __attribute__((ext_vector_type(4)));

__device__ __forceinline__ u16 f2bfu(float x) {
  union { float f; unsigned u; } c; c.f = x;
  unsigned u = c.u;
  u = u + 0x7FFFu + ((u >> 16) & 1u);   // RNE
  return (u16)(u >> 16);
}

__device__ __forceinline__ bf16x8 ldsFrag(const u16* p) {
  u16x8 t = *(const u16x8*)p;
  return __builtin_bit_cast(bf16x8, t);
}

// ---------------------------------------------------------------------------
// Per-(b,h) gate preprocessing: fc = cumsum(logsigmoid(f)); a = i - fc;
// c = cummax(a); nfl = exp(-(c+fc)) = exp(-m).  One block per head, T=2048.
// ---------------------------------------------------------------------------
__global__ __launch_bounds__(256) void gate_scan_kernel(
    const float* __restrict__ ig, const float* __restrict__ fg,
    float* __restrict__ a_out, float* __restrict__ c_out,
    float* __restrict__ nfl_out)
{
  const int bh  = blockIdx.x;
  const int tid = threadIdx.x;
  const int base = bh * T_SEQ + tid * 8;
  __shared__ float sbuf[256];

  // local inclusive cumsum of logsigmoid(f)
  float lf[8];
  float run = 0.f;
#pragma unroll
  for (int j = 0; j < 8; ++j) {
    float x  = fg[base + j];
    float ls = fminf(x, 0.f) - log1pf(expf(-fabsf(x)));  // stable logsigmoid
    run += ls; lf[j] = run;
  }
  sbuf[tid] = run; __syncthreads();
  for (int off = 1; off < 256; off <<= 1) {
    float t = (tid >= off) ? sbuf[tid - off] : 0.f;
    __syncthreads();
    sbuf[tid] += t;
    __syncthreads();
  }
  const float excl = (tid > 0) ? sbuf[tid - 1] : 0.f;
  __syncthreads();

  float fc[8], cm[8];
  float runm = -INFINITY;
#pragma unroll
  for (int j = 0; j < 8; ++j) {
    fc[j] = excl + lf[j];
    float av = ig[base + j] - fc[j];
    a_out[base + j] = av;
    runm = fmaxf(runm, av);
    cm[j] = runm;
  }
  sbuf[tid] = runm; __syncthreads();
  for (int off = 1; off < 256; off <<= 1) {
    float t = (tid >= off) ? sbuf[tid - off] : -INFINITY;
    __syncthreads();
    sbuf[tid] = fmaxf(sbuf[tid], t);
    __syncthreads();
  }
  const float exclm = (tid > 0) ? sbuf[tid - 1] : -INFINITY;
#pragma unroll
  for (int j = 0; j < 8; ++j) {
    float c = fmaxf(exclm, cm[j]);
    c_out[base + j]   = c;
    nfl_out[base + j] = expf(-(c + fc[j]));   // exp(-m)
  }
}

// ---------------------------------------------------------------------------
// Flash-style mLSTM forward.  Block = 256 thr = 4 waves; each wave owns a
// 16-row Q strip of a 64-row query tile.  Key tiles of 64 streamed via LDS.
// MFMA 16x16x32 bf16; layouts per learn_hip m89/m91/m120:
//   A-frag:  A[m = lane&15][k = quad*8 + j]
//   B-frag:  B[k = quad*8 + j][n = lane&15]
//   C/D:     row m = quad*4 + reg, col n = lane&15
// ---------------------------------------------------------------------------
__global__ __launch_bounds__(256, 3) void mlstm_fwd_kernel(
    const float* __restrict__ qg, const float* __restrict__ kg,
    const float* __restrict__ vg,
    const float* __restrict__ ag, const float* __restrict__ cg,
    const float* __restrict__ nflg, float* __restrict__ out)
{
  const int bh   = blockIdx.y;
  const int qt   = (int)gridDim.x - 1 - (int)blockIdx.x;  // heavy tiles first
  const int tid  = (int)threadIdx.x;
  const int wave = tid >> 6, lane = tid & 63;
  const int quad = lane >> 4, l16 = lane & 15;

  // strides: Ks 136 (272B, 16B-mult), Vt/Pl 72 (144B, 16B-mult) -> aligned b128
  __shared__ __align__(16) u16 Ks[64 * 136];
  __shared__ __align__(16) u16 Vt[128 * 72];
  __shared__ __align__(16) u16 Pl[4][16 * 72];
  __shared__ float aS[64];

  const int hoff  = bh * T_SEQ * DHEAD;
  const int goff  = bh * T_SEQ;
  const int qrowA = qt * 64 + wave * 16 + l16;      // A-frag query row
  const int trow0 = qt * 64 + wave * 16 + quad * 4; // C-layout row base

  // Q strip -> A-frags (4 chunks of K=32), fp32 -> bf16
  bf16x8 qf[4];
  {
    const float* qp = qg + hoff + qrowA * DHEAD + quad * 8;
#pragma unroll
    for (int kc = 0; kc < 4; ++kc) {
      const float4 x0 = *(const float4*)(qp + kc * 32);
      const float4 x1 = *(const float4*)(qp + kc * 32 + 4);
      u16x8 t;
      t[0] = f2bfu(x0.x); t[1] = f2bfu(x0.y); t[2] = f2bfu(x0.z); t[3] = f2bfu(x0.w);
      t[4] = f2bfu(x1.x); t[5] = f2bfu(x1.y); t[6] = f2bfu(x1.z); t[7] = f2bfu(x1.w);
      qf[kc] = __builtin_bit_cast(bf16x8, t);
    }
  }
  float cr[4];
#pragma unroll
  for (int r = 0; r < 4; ++r) cr[r] = cg[goff + trow0 + r];

  f32x4 oa[8];
#pragma unroll
  for (int nv = 0; nv < 8; ++nv) oa[nv] = (f32x4){0.f, 0.f, 0.f, 0.f};
  float rs[4] = {0.f, 0.f, 0.f, 0.f};

  const int stage_row = tid >> 2, stage_c0 = (tid & 3) * 4;  // K staging map
  const int vt_c0 = (tid & 31) * 4, vt_r0 = (tid >> 5) * 8;  // V transpose map

  for (int kt = 0; kt <= qt; ++kt) {
    __syncthreads();   // previous tile's LDS reads complete
    // ---- stage K tile (row-major bf16) ----
    {
      const float* kp = kg + hoff + (kt * 64 + stage_row) * DHEAD + stage_c0;
      u16* dst = &Ks[stage_row * 136 + stage_c0];
#pragma unroll
      for (int i = 0; i < 8; ++i) {
        const float4 x = *(const float4*)(kp + i * 16);
        u16x4 p; p[0] = f2bfu(x.x); p[1] = f2bfu(x.y); p[2] = f2bfu(x.z); p[3] = f2bfu(x.w);
        *(u16x4*)(dst + i * 16) = p;
      }
    }
    // ---- stage V tile transposed: Vt[col][key] ----
    {
      const float* vp = vg + hoff + (kt * 64 + vt_r0) * DHEAD + vt_c0;
      u16 tv[4][8];
#pragma unroll
      for (int rr = 0; rr < 8; ++rr) {
        const float4 x = *(const float4*)(vp + rr * DHEAD);
        tv[0][rr] = f2bfu(x.x); tv[1][rr] = f2bfu(x.y);
        tv[2][rr] = f2bfu(x.z); tv[3][rr] = f2bfu(x.w);
      }
#pragma unroll
      for (int j = 0; j < 4; ++j) {
        u16x8 p;
#pragma unroll
        for (int rr = 0; rr < 8; ++rr) p[rr] = tv[j][rr];
        *(u16x8*)(&Vt[(vt_c0 + j) * 72 + vt_r0]) = p;
      }
    }
    if (tid < 64) aS[tid] = ag[goff + kt * 64 + tid];
    __syncthreads();

    const bool diag = (kt == qt);
    // ---- S = Q K^T, then P = scale * S * exp(a[s]-c[t]), to per-wave LDS ----
#pragma unroll
    for (int nc = 0; nc < 4; ++nc) {
      f32x4 s = (f32x4){0.f, 0.f, 0.f, 0.f};
#pragma unroll
      for (int kc = 0; kc < 4; ++kc) {
        const bf16x8 bk = ldsFrag(&Ks[(nc * 16 + l16) * 136 + kc * 32 + quad * 8]);
        s = __builtin_amdgcn_mfma_f32_16x16x32_bf16(qf[kc], bk, s, 0, 0, 0);
      }
      const int scol = nc * 16 + l16;        // local key col
      const float asv = aS[scol];
#pragma unroll
      for (int r = 0; r < 4; ++r) {
        float p = s[r] * (SCALE * __expf(asv - cr[r]));  // exponent <= 0 if causal
        if (diag && (kt * 64 + scol > trow0 + r)) p = 0.f;
        rs[r] += p;
        Pl[wave][(quad * 4 + r) * 72 + scol] = f2bfu(p);
      }
    }
    // ---- O += P V  (P re-read from LDS in A-frag layout) ----
#pragma unroll
    for (int kk = 0; kk < 2; ++kk) {
      const bf16x8 pa = ldsFrag(&Pl[wave][l16 * 72 + kk * 32 + quad * 8]);
#pragma unroll
      for (int nv = 0; nv < 8; ++nv) {
        const bf16x8 bv = ldsFrag(&Vt[(nv * 16 + l16) * 72 + kk * 32 + quad * 8]);
        oa[nv] = __builtin_amdgcn_mfma_f32_16x16x32_bf16(pa, bv, oa[nv], 0, 0, 0);
      }
    }
  }

  // ---- epilogue: rowsum reduce across the 16 lanes sharing rows ----
#pragma unroll
  for (int r = 0; r < 4; ++r) {
    float x = rs[r];
#pragma unroll
    for (int off = 1; off < 16; off <<= 1) x += __shfl_xor(x, off, 64);
    rs[r] = x;
  }
  float inv[4];
#pragma unroll
  for (int r = 0; r < 4; ++r) {
    const float nf = nflg[goff + trow0 + r];          // exp(-m[t])
    inv[r] = 1.f / fmaxf(fabsf(rs[r]), nf);
  }
  float* op = out + hoff;
#pragma unroll
  for (int nv = 0; nv < 8; ++nv) {
#pragma unroll
    for (int r = 0; r < 4; ++r) {
      op[(trow0 + r) * DHEAD + nv * 16 + l16] = oa[nv][r] * inv[r];
    }
  }
}

// ---------------------------------------------------------------------------
extern "C" void kernel_launch(void* const* d_in, const int* in_sizes, int n_in,
                              void* d_out, int out_size, void* d_ws, size_t ws_size,
                              hipStream_t stream) {
  const float* q  = (const float*)d_in[0];
  const float* k  = (const float*)d_in[1];
  const float* v  = (const float*)d_in[2];
  const float* ig = (const float*)d_in[3];
  const float* fg = (const float*)d_in[4];

  float* a_ws   = (float*)d_ws;            // [NBH*T]
  float* c_ws   = a_ws + NBH * T_SEQ;      // [NBH*T]
  float* nfl_ws = c_ws + NBH * T_SEQ;      // [NBH*T]

  gate_scan_kernel<<<dim3(NBH), dim3(256), 0, stream>>>(ig, fg, a_ws, c_ws, nfl_ws);
  mlstm_fwd_kernel<<<dim3(T_SEQ / 64, NBH), dim3(256), 0, stream>>>(
      q, k, v, a_ws, c_ws, nfl_ws, (float*)d_out);
}

// Round 2
// 154.523 us; speedup vs baseline: 1.4124x; 1.4124x over previous
//
#include <hip/hip_runtime.h>

#define T_SEQ 2048
#define DHEAD 128
#define NBH 16
#define SCALE 0.08838834764831845f

typedef unsigned short u16;
typedef u16 u16x4 __attribute__((ext_vector_type(4)));
typedef u16 u16x8 __attribute__((ext_vector_type(8)));
typedef __bf16 bf16x8 __attribute__((ext_vector_type(8)));
typedef float f32x4 __attribute__((ext_vector_type(4)));

__device__ __forceinline__ u16 f2bfu(float x) {
  union { float f; unsigned u; } c; c.f = x;
  unsigned u = c.u;
  u = u + 0x7FFFu + ((u >> 16) & 1u);   // RNE
  return (u16)(u >> 16);
}

__device__ __forceinline__ bf16x8 ldsFrag(const u16* p) {
  u16x8 t = *(const u16x8*)p;
  return __builtin_bit_cast(bf16x8, t);
}

__device__ __forceinline__ void gld_lds16(const void* g, void* l) {
  __builtin_amdgcn_global_load_lds(
      (__attribute__((address_space(1))) const unsigned int*)g,
      (__attribute__((address_space(3))) unsigned int*)l, 16, 0, 0);
}

// ---------------------------------------------------------------------------
// Gate scan: fc=cumsum(logsigmoid(f)); a=i-fc; c=cummax(a); nfl=exp(-(c+fc)).
// ---------------------------------------------------------------------------
__global__ __launch_bounds__(256) void gate_scan_kernel(
    const float* __restrict__ ig, const float* __restrict__ fg,
    float* __restrict__ a_out, float* __restrict__ c_out,
    float* __restrict__ nfl_out)
{
  const int bh  = blockIdx.x;
  const int tid = threadIdx.x;
  const int base = bh * T_SEQ + tid * 8;
  __shared__ float sbuf[256];

  float lf[8];
  float run = 0.f;
#pragma unroll
  for (int j = 0; j < 8; ++j) {
    float x  = fg[base + j];
    float ls = fminf(x, 0.f) - log1pf(expf(-fabsf(x)));
    run += ls; lf[j] = run;
  }
  sbuf[tid] = run; __syncthreads();
  for (int off = 1; off < 256; off <<= 1) {
    float t = (tid >= off) ? sbuf[tid - off] : 0.f;
    __syncthreads();
    sbuf[tid] += t;
    __syncthreads();
  }
  const float excl = (tid > 0) ? sbuf[tid - 1] : 0.f;
  __syncthreads();

  float fc[8], cm[8];
  float runm = -INFINITY;
#pragma unroll
  for (int j = 0; j < 8; ++j) {
    fc[j] = excl + lf[j];
    float av = ig[base + j] - fc[j];
    a_out[base + j] = av;
    runm = fmaxf(runm, av);
    cm[j] = runm;
  }
  sbuf[tid] = runm; __syncthreads();
  for (int off = 1; off < 256; off <<= 1) {
    float t = (tid >= off) ? sbuf[tid - off] : -INFINITY;
    __syncthreads();
    sbuf[tid] = fmaxf(sbuf[tid], t);
    __syncthreads();
  }
  const float exclm = (tid > 0) ? sbuf[tid - 1] : -INFINITY;
#pragma unroll
  for (int j = 0; j < 8; ++j) {
    float c = fmaxf(exclm, cm[j]);
    c_out[base + j]   = c;
    nfl_out[base + j] = expf(-(c + fc[j]));
  }
}

// ---------------------------------------------------------------------------
// Pre-pass: K fp32 -> bf16 (same layout).
// ---------------------------------------------------------------------------
__global__ __launch_bounds__(256) void cvt_k_kernel(
    const float* __restrict__ src, u16* __restrict__ dst)
{
  const int i = (blockIdx.x * 256 + threadIdx.x) * 4;
  const float4 x = *(const float4*)(src + i);
  u16x4 p; p[0] = f2bfu(x.x); p[1] = f2bfu(x.y); p[2] = f2bfu(x.z); p[3] = f2bfu(x.w);
  *(u16x4*)(dst + i) = p;
}

// ---------------------------------------------------------------------------
// Pre-pass: V fp32 [bh][key][n] -> bf16 transposed Vt [bh][n][key].
// ---------------------------------------------------------------------------
__global__ __launch_bounds__(256) void cvt_vt_kernel(
    const float* __restrict__ v, u16* __restrict__ vt)
{
  const int bh = blockIdx.y, kt = blockIdx.x, tid = threadIdx.x;
  __shared__ __align__(16) u16 L[128 * 72];
  const int n0 = (tid & 31) * 4, k0 = (tid >> 5) * 8;
  const float* vp = v + ((size_t)bh * T_SEQ + kt * 64 + k0) * DHEAD + n0;
  u16 tv[4][8];
#pragma unroll
  for (int rr = 0; rr < 8; ++rr) {
    const float4 x = *(const float4*)(vp + rr * DHEAD);
    tv[0][rr] = f2bfu(x.x); tv[1][rr] = f2bfu(x.y);
    tv[2][rr] = f2bfu(x.z); tv[3][rr] = f2bfu(x.w);
  }
#pragma unroll
  for (int j = 0; j < 4; ++j) {
    u16x8 p;
#pragma unroll
    for (int rr = 0; rr < 8; ++rr) p[rr] = tv[j][rr];
    *(u16x8*)(&L[(n0 + j) * 72 + k0]) = p;
  }
  __syncthreads();
  const int row = tid >> 1, s0 = (tid & 1) * 32;
  u16* op = vt + ((size_t)bh * DHEAD + row) * T_SEQ + kt * 64 + s0;
#pragma unroll
  for (int i = 0; i < 4; ++i)
    *(u16x8*)(op + i * 8) = *(const u16x8*)(&L[row * 72 + s0 + i * 8]);
}

// ---------------------------------------------------------------------------
// Main flash mLSTM.  Double-buffered LDS, async global_load_lds staging (FAST)
// or register-staged fp32 fallback.  XOR block swizzle (db ^ (key&7)) keeps
// global_load_lds lane-contiguity AND conflict-free b128 reads.
// ---------------------------------------------------------------------------
template <bool FAST>
__global__ __launch_bounds__(256, 2) void mlstm_fwd_kernel(
    const float* __restrict__ qg, const float* __restrict__ kg,
    const float* __restrict__ vg,
    const u16* __restrict__ kbf, const u16* __restrict__ vtbf,
    const float* __restrict__ ag, const float* __restrict__ cg,
    const float* __restrict__ nflg, float* __restrict__ out)
{
  // XCD-aware decode: bx&7 -> XCD slot; 2 heads/XCD, heavy q-tiles first.
  const int bx = (int)blockIdx.x;
  const int xs = bx & 7, js = bx >> 3;
  const int bh = xs + 8 * (js & 1);
  const int qt = 31 - (js >> 1);

  const int tid  = (int)threadIdx.x;
  const int wave = tid >> 6, lane = tid & 63;
  const int quad = lane >> 4, l16 = lane & 15;

  __shared__ __align__(16) u16 KB[2][64 * 128];   // swizzled 16B blocks
  __shared__ __align__(16) u16 VB[2][128 * 64];   // swizzled 16B blocks
  __shared__ __align__(16) u16 Pl[4][16 * 72];

  const size_t hoff = (size_t)bh * T_SEQ * DHEAD;
  const int goff = bh * T_SEQ;
  const int qrowA = qt * 64 + wave * 16 + l16;
  const int trow0 = qt * 64 + wave * 16 + quad * 4;

  // Q strip -> A-frags
  bf16x8 qf[4];
  {
    const float* qp = qg + hoff + (size_t)qrowA * DHEAD + quad * 8;
#pragma unroll
    for (int kc = 0; kc < 4; ++kc) {
      const float4 x0 = *(const float4*)(qp + kc * 32);
      const float4 x1 = *(const float4*)(qp + kc * 32 + 4);
      u16x8 t;
      t[0] = f2bfu(x0.x); t[1] = f2bfu(x0.y); t[2] = f2bfu(x0.z); t[3] = f2bfu(x0.w);
      t[4] = f2bfu(x1.x); t[5] = f2bfu(x1.y); t[6] = f2bfu(x1.z); t[7] = f2bfu(x1.w);
      qf[kc] = __builtin_bit_cast(bf16x8, t);
    }
  }
  float cr[4];
#pragma unroll
  for (int r = 0; r < 4; ++r) cr[r] = cg[goff + trow0 + r];

  f32x4 oa[8];
#pragma unroll
  for (int nv = 0; nv < 8; ++nv) oa[nv] = (f32x4){0.f, 0.f, 0.f, 0.f};
  float rs[4] = {0.f, 0.f, 0.f, 0.f};

  // fallback staging registers
  float4 kr[8], vr[8];
  const int fb_keyb = tid >> 4;            // K fallback: base key group
  const int fb_db   = (tid & 15) ^ ((tid >> 4) & 7);
  const int fb_n0 = (tid & 31) * 4, fb_k0 = (tid >> 5) * 8;

  // ---- staging issue (FAST: async DMA to LDS buf; fallback: global->regs) --
  auto stage_issue = [&](int kt, int b) {
    if (FAST) {
      const u16* ks = kbf + ((size_t)goff + kt * 64) * DHEAD;
      const u16* vs = vtbf + (size_t)bh * DHEAD * T_SEQ + kt * 64;
#pragma unroll
      for (int j = 0; j < 4; ++j) {
        const int B = (wave * 4 + j) * 64 + lane;
        { // K: block B -> key=B>>4, stored-dim-block = (B&15)^(key&7)
          const int key = B >> 4;
          const int db = (B & 15) ^ (key & 7);
          gld_lds16(ks + (size_t)key * DHEAD + db * 8, &KB[b][(wave * 4 + j) * 512]);
        }
        { // V: block B -> n=B>>3, stored-key-block = (B&7)^(n&7)
          const int n = B >> 3;
          const int kb = (B & 7) ^ (n & 7);
          gld_lds16(vs + (size_t)n * T_SEQ + kb * 8, &VB[b][(wave * 4 + j) * 512]);
        }
      }
    } else {
      const float* kp = kg + hoff + (size_t)(kt * 64) * DHEAD;
      const float* vp = vg + hoff + (size_t)(kt * 64 + fb_k0) * DHEAD + fb_n0;
#pragma unroll
      for (int jb = 0; jb < 4; ++jb) {
        const int key = fb_keyb + 16 * jb;
        kr[2 * jb]     = *(const float4*)(kp + (size_t)key * DHEAD + fb_db * 8);
        kr[2 * jb + 1] = *(const float4*)(kp + (size_t)key * DHEAD + fb_db * 8 + 4);
      }
#pragma unroll
      for (int rr = 0; rr < 8; ++rr) vr[rr] = *(const float4*)(vp + rr * DHEAD);
    }
  };
  // ---- staging commit (fallback only: convert regs -> LDS) ----
  auto stage_commit = [&](int b) {
    if (!FAST) {
#pragma unroll
      for (int jb = 0; jb < 4; ++jb) {
        const int key = fb_keyb + 16 * jb;
        u16x8 p;
        p[0] = f2bfu(kr[2*jb].x);   p[1] = f2bfu(kr[2*jb].y);
        p[2] = f2bfu(kr[2*jb].z);   p[3] = f2bfu(kr[2*jb].w);
        p[4] = f2bfu(kr[2*jb+1].x); p[5] = f2bfu(kr[2*jb+1].y);
        p[6] = f2bfu(kr[2*jb+1].z); p[7] = f2bfu(kr[2*jb+1].w);
        *(u16x8*)(&KB[b][(key * 16 + (tid & 15)) * 8]) = p;
      }
      u16 tv[4][8];
#pragma unroll
      for (int rr = 0; rr < 8; ++rr) {
        tv[0][rr] = f2bfu(vr[rr].x); tv[1][rr] = f2bfu(vr[rr].y);
        tv[2][rr] = f2bfu(vr[rr].z); tv[3][rr] = f2bfu(vr[rr].w);
      }
      const int kb = fb_k0 >> 3;
#pragma unroll
      for (int j = 0; j < 4; ++j) {
        const int n = fb_n0 + j;
        u16x8 p;
#pragma unroll
        for (int rr = 0; rr < 8; ++rr) p[rr] = tv[j][rr];
        *(u16x8*)(&VB[b][(n * 8 + (kb ^ (n & 7))) * 8]) = p;
      }
    }
  };

  stage_issue(0, 0);
  stage_commit(0);
  __syncthreads();   // drains DMA (FAST) / aligns LDS writes (fallback)

  for (int kt = 0; kt <= qt; ++kt) {
    const int b = kt & 1;
    if (kt < qt) stage_issue(kt + 1, b ^ 1);

    float an[4];
#pragma unroll
    for (int nc = 0; nc < 4; ++nc) an[nc] = ag[goff + kt * 64 + nc * 16 + l16];

    const bool diag = (kt == qt);
#pragma unroll
    for (int nc = 0; nc < 4; ++nc) {
      f32x4 s = (f32x4){0.f, 0.f, 0.f, 0.f};
      const int key = nc * 16 + l16;
#pragma unroll
      for (int kc = 0; kc < 4; ++kc) {
        const int db = (kc * 4 + quad) ^ (l16 & 7);
        const bf16x8 bk = ldsFrag(&KB[b][(key * 16 + db) * 8]);
        s = __builtin_amdgcn_mfma_f32_16x16x32_bf16(qf[kc], bk, s, 0, 0, 0);
      }
      const float asv = an[nc];
      const int scol = nc * 16 + l16;
#pragma unroll
      for (int r = 0; r < 4; ++r) {
        float p = s[r] * (SCALE * __expf(asv - cr[r]));
        if (diag && (kt * 64 + scol > trow0 + r)) p = 0.f;
        rs[r] += p;
        Pl[wave][(quad * 4 + r) * 72 + scol] = f2bfu(p);
      }
    }
#pragma unroll
    for (int kk = 0; kk < 2; ++kk) {
      const bf16x8 pa = ldsFrag(&Pl[wave][l16 * 72 + kk * 32 + quad * 8]);
#pragma unroll
      for (int nv = 0; nv < 8; ++nv) {
        const int n = nv * 16 + l16;
        const int kb = (kk * 4 + quad) ^ (l16 & 7);
        const bf16x8 bv = ldsFrag(&VB[b][(n * 8 + kb) * 8]);
        oa[nv] = __builtin_amdgcn_mfma_f32_16x16x32_bf16(pa, bv, oa[nv], 0, 0, 0);
      }
    }
    if (kt < qt) stage_commit(b ^ 1);
    __syncthreads();   // DMA prefetch drained; all waves done with buf b
  }

  // ---- epilogue ----
#pragma unroll
  for (int r = 0; r < 4; ++r) {
    float x = rs[r];
#pragma unroll
    for (int off = 1; off < 16; off <<= 1) x += __shfl_xor(x, off, 64);
    rs[r] = x;
  }
  float inv[4];
#pragma unroll
  for (int r = 0; r < 4; ++r) {
    const float nf = nflg[goff + trow0 + r];
    inv[r] = 1.f / fmaxf(fabsf(rs[r]), nf);
  }
  float* op = out + hoff;
#pragma unroll
  for (int nv = 0; nv < 8; ++nv) {
#pragma unroll
    for (int r = 0; r < 4; ++r) {
      op[(size_t)(trow0 + r) * DHEAD + nv * 16 + l16] = oa[nv][r] * inv[r];
    }
  }
}

// ---------------------------------------------------------------------------
extern "C" void kernel_launch(void* const* d_in, const int* in_sizes, int n_in,
                              void* d_out, int out_size, void* d_ws, size_t ws_size,
                              hipStream_t stream) {
  const float* q  = (const float*)d_in[0];
  const float* k  = (const float*)d_in[1];
  const float* v  = (const float*)d_in[2];
  const float* ig = (const float*)d_in[3];
  const float* fg = (const float*)d_in[4];

  const size_t gate_bytes = (size_t)3 * NBH * T_SEQ * sizeof(float);
  const size_t kv_elems   = (size_t)NBH * T_SEQ * DHEAD;
  const bool fast = ws_size >= gate_bytes + 2 * kv_elems * sizeof(u16);

  float* a_ws   = (float*)d_ws;
  float* c_ws   = a_ws + NBH * T_SEQ;
  float* nfl_ws = c_ws + NBH * T_SEQ;
  u16* kbf  = (u16*)((char*)d_ws + gate_bytes);
  u16* vtbf = kbf + kv_elems;

  gate_scan_kernel<<<dim3(NBH), dim3(256), 0, stream>>>(ig, fg, a_ws, c_ws, nfl_ws);
  if (fast) {
    cvt_k_kernel<<<dim3((unsigned)(kv_elems / 1024)), dim3(256), 0, stream>>>(k, kbf);
    cvt_vt_kernel<<<dim3(T_SEQ / 64, NBH), dim3(256), 0, stream>>>(v, vtbf);
    mlstm_fwd_kernel<true><<<dim3(512), dim3(256), 0, stream>>>(
        q, k, v, kbf, vtbf, a_ws, c_ws, nfl_ws, (float*)d_out);
  } else {
    mlstm_fwd_kernel<false><<<dim3(512), dim3(256), 0, stream>>>(
        q, k, v, kbf, vtbf, a_ws, c_ws, nfl_ws, (float*)d_out);
  }
}